// Round 1
// baseline (1247.954 us; speedup 1.0000x reference)
//
#include <hip/hip_runtime.h>
#include <hip/hip_bf16.h>
#include <stdint.h>

#define N_NODES 100000
#define N_EDGES 1600000
#define IN_DIM  384
#define HID_DIM 64

// ---------------- runtime dtype detection ----------------
// flags[0]: edge_index is int64 (1) or int32 (0)
// flags[1]: mask mode: 0 = 16-bit (bf16/f16), 2 = f32, 3 = u8, 4 = i32
__global__ void k_detect(const uint32_t* __restrict__ ei,
                         const uint32_t* __restrict__ m1,
                         int* __restrict__ flags) {
    int l = threadIdx.x;  // 64 threads, 1 block
    uint32_t hi = ei[2 * l + 1];
    int ei64 = __all(hi == 0u);

    uint32_t maxb = 0;
    int bf = 0, f16 = 0, hib = 0;
    for (int i = 0; i < 4; ++i) {
        uint32_t w = m1[l * 4 + i];
        uint32_t b0 = w & 0xffu, b1 = (w >> 8) & 0xffu,
                 b2 = (w >> 16) & 0xffu, b3 = (w >> 24) & 0xffu;
        uint32_t mb = b0 > b1 ? b0 : b1;
        uint32_t mb2 = b2 > b3 ? b2 : b3;
        mb = mb > mb2 ? mb : mb2;
        maxb = maxb > mb ? maxb : mb;
        if ((w & 0xffffu) == 0x3f80u) bf = 1;   // low half == 1.0 bf16
        if ((w & 0xffffu) == 0x3c00u) f16 = 1;  // low half == 1.0 f16
        if ((b1 | b2 | b3) != 0u) hib = 1;
    }
    int small  = __all(maxb <= 1u);
    int anybf  = __any(bf);
    int anyf16 = __any(f16);
    int anyhib = __any(hib);
    if (l == 0) {
        flags[0] = ei64;
        int mm;
        if (small)                 mm = anyhib ? 3 : 4;  // u8 vs i32
        else if (anybf || anyf16)  mm = 0;               // 16-bit
        else                       mm = 2;               // f32
        flags[1] = mm;
    }
}

// mask value already folded with dropout scale 1/(1-0.5) = 2.0
__device__ __forceinline__ float mask_at(const void* p, int mode, long idx) {
    if (mode == 0) return ((const uint16_t*)p)[idx] ? 2.0f : 0.0f;
    if (mode == 2) return ((const float*)p)[idx] != 0.0f ? 2.0f : 0.0f;
    if (mode == 3) return ((const uint8_t*)p)[idx] ? 2.0f : 0.0f;
    return ((const int*)p)[idx] ? 2.0f : 0.0f;
}

// ---------------- GEMM1: H = (x .* m1 * 2) @ W1  [N,384]x[384,64] ----------------
// 32 nodes per block, 256 threads: 64 cols x 4 node-groups of 8 rows each.
__global__ __launch_bounds__(256) void k1_gemm(
        const float* __restrict__ x, const void* __restrict__ m1,
        const float* __restrict__ W1, float* __restrict__ H,
        const int* __restrict__ flags) {
    __shared__ float xm[32][IN_DIM];
    const int mmode = flags[1];
    const int node0 = blockIdx.x * 32;

    // stage masked+scaled x tile
    for (int i = threadIdx.x; i < 32 * (IN_DIM / 4); i += 256) {
        int r = i / (IN_DIM / 4), c4 = i % (IN_DIM / 4);
        long n = node0 + r;
        float4 v = ((const float4*)x)[n * (IN_DIM / 4) + c4];
        long base = n * IN_DIM + c4 * 4;
        float4 msk;
        if (mmode == 0) {
            ushort4 mu = ((const ushort4*)m1)[n * (IN_DIM / 4) + c4];
            msk.x = mu.x ? 2.0f : 0.0f; msk.y = mu.y ? 2.0f : 0.0f;
            msk.z = mu.z ? 2.0f : 0.0f; msk.w = mu.w ? 2.0f : 0.0f;
        } else {
            msk.x = mask_at(m1, mmode, base + 0);
            msk.y = mask_at(m1, mmode, base + 1);
            msk.z = mask_at(m1, mmode, base + 2);
            msk.w = mask_at(m1, mmode, base + 3);
        }
        v.x *= msk.x; v.y *= msk.y; v.z *= msk.z; v.w *= msk.w;
        *(float4*)&xm[r][c4 * 4] = v;
    }
    __syncthreads();

    const int c = threadIdx.x & 63;
    const int g = threadIdx.x >> 6;  // rows g*8 .. g*8+7
    float acc[8];
#pragma unroll
    for (int r = 0; r < 8; ++r) acc[r] = 0.0f;

    for (int k = 0; k < IN_DIM; k += 4) {
        float w0 = W1[(k + 0) * 64 + c];
        float w1 = W1[(k + 1) * 64 + c];
        float w2 = W1[(k + 2) * 64 + c];
        float w3 = W1[(k + 3) * 64 + c];
#pragma unroll
        for (int r = 0; r < 8; ++r) {
            float4 xv = *(const float4*)&xm[g * 8 + r][k];
            acc[r] = fmaf(xv.x, w0, acc[r]);
            acc[r] = fmaf(xv.y, w1, acc[r]);
            acc[r] = fmaf(xv.z, w2, acc[r]);
            acc[r] = fmaf(xv.w, w3, acc[r]);
        }
    }
#pragma unroll
    for (int r = 0; r < 8; ++r)
        H[(long)(node0 + g * 8 + r) * 64 + c] = acc[r];
}

// ---------------- edge scatter: dest[dst] += Hsrc[src] * ew  ----------------
// one wave per edge, lane = column
__global__ __launch_bounds__(256) void k_scatter(
        const float* __restrict__ Hsrc, const void* __restrict__ ei,
        const float* __restrict__ ew, float* __restrict__ dest,
        const int* __restrict__ flags) {
    const int mode64 = flags[0];
    const int lane = threadIdx.x & 63;
    const long wid = (long)blockIdx.x * 4 + (threadIdx.x >> 6);
    const long nw = (long)gridDim.x * 4;
    const int* p32 = (const int*)ei;
    for (long e = wid; e < N_EDGES; e += nw) {
        int s, d;
        if (mode64) { s = p32[2 * e]; d = p32[2 * (N_EDGES + e)]; }
        else        { s = p32[e];     d = p32[N_EDGES + e]; }
        float w = ew[e];
        float v = Hsrc[(long)s * 64 + lane] * w;
        atomicAdd(&dest[(long)d * 64 + lane], v);
    }
}

// ---------------- fused relu/dropout/GEMM2: H2 = (relu(agg+b1).*m2*2) @ W2 ----------------
__global__ __launch_bounds__(256) void k3_mlp(
        const float* __restrict__ agg, const float* __restrict__ b1,
        const void* __restrict__ m2, const float* __restrict__ W2,
        float* __restrict__ H2, const int* __restrict__ flags) {
    __shared__ float w2s[64 * 64];
    __shared__ float vbuf[4][64];
    const int mmode = flags[1];
    for (int i = threadIdx.x; i < 4096; i += 256) w2s[i] = W2[i];
    __syncthreads();

    const int lane = threadIdx.x & 63;
    const int w = threadIdx.x >> 6;
    const float bc = b1[lane];
    const long wid = (long)blockIdx.x * 4 + w;
    const long nw = (long)gridDim.x * 4;
    for (long n = wid; n < N_NODES; n += nw) {
        float u = agg[n * 64 + lane] + bc;
        u = u > 0.0f ? u : 0.0f;
        u *= mask_at(m2, mmode, n * 64 + lane);
        vbuf[w][lane] = u;
        float acc = 0.0f;
#pragma unroll
        for (int j = 0; j < 64; j += 4) {
            float4 v4 = *(const float4*)&vbuf[w][j];
            acc = fmaf(v4.x, w2s[(j + 0) * 64 + lane], acc);
            acc = fmaf(v4.y, w2s[(j + 1) * 64 + lane], acc);
            acc = fmaf(v4.z, w2s[(j + 2) * 64 + lane], acc);
            acc = fmaf(v4.w, w2s[(j + 3) * 64 + lane], acc);
        }
        H2[n * 64 + lane] = acc;
    }
}

// ---------------- init output with bias b2 ----------------
__global__ void k_init_out(float* __restrict__ out, const float* __restrict__ b2) {
    const long total = (long)N_NODES * 16;  // float4 count
    for (long j = (long)blockIdx.x * 256 + threadIdx.x; j < total;
         j += (long)gridDim.x * 256) {
        ((float4*)out)[j] = ((const float4*)b2)[j & 15];
    }
}

extern "C" void kernel_launch(void* const* d_in, const int* in_sizes, int n_in,
                              void* d_out, int out_size, void* d_ws, size_t ws_size,
                              hipStream_t stream) {
    const float* x  = (const float*)d_in[0];
    const void*  ei = d_in[1];
    const float* ew = (const float*)d_in[2];
    const float* W1 = (const float*)d_in[3];
    const float* b1 = (const float*)d_in[4];
    const float* W2 = (const float*)d_in[5];
    const float* b2 = (const float*)d_in[6];
    const void*  m1 = d_in[7];
    const void*  m2 = d_in[8];
    float* out = (float*)d_out;

    char* ws = (char*)d_ws;
    int*   flags = (int*)ws;
    float* H     = (float*)(ws + 256);
    float* AGG   = (float*)(ws + 256 + (size_t)N_NODES * 64 * 4);

    hipLaunchKernelGGL(k_detect, dim3(1), dim3(64), 0, stream,
                       (const uint32_t*)ei, (const uint32_t*)m1, flags);
    hipMemsetAsync(AGG, 0, (size_t)N_NODES * 64 * 4, stream);
    hipLaunchKernelGGL(k1_gemm, dim3(N_NODES / 32), dim3(256), 0, stream,
                       x, m1, W1, H, flags);
    hipLaunchKernelGGL(k_scatter, dim3(4096), dim3(256), 0, stream,
                       H, ei, ew, AGG, flags);
    hipLaunchKernelGGL(k3_mlp, dim3(1024), dim3(256), 0, stream,
                       AGG, b1, m2, W2, H, flags);
    hipLaunchKernelGGL(k_init_out, dim3(2048), dim3(256), 0, stream, out, b2);
    hipLaunchKernelGGL(k_scatter, dim3(4096), dim3(256), 0, stream,
                       H, ei, ew, out, flags);
}

// Round 2
// 971.389 us; speedup vs baseline: 1.2847x; 1.2847x over previous
//
#include <hip/hip_runtime.h>
#include <hip/hip_bf16.h>
#include <stdint.h>

#define N_NODES 100000
#define N_EDGES 1600000
#define IN_DIM  384
#define HID_DIM 64
#define SCAN_NB 391   // ceil(100000/256)

// ---------------- runtime dtype detection ----------------
// flags[0]: edge_index is int64 (1) or int32 (0)
// flags[1]: mask mode: 0 = 16-bit (bf16/f16), 2 = f32, 3 = u8, 4 = i32
__global__ void k_detect(const uint32_t* __restrict__ ei,
                         const uint32_t* __restrict__ m1,
                         int* __restrict__ flags) {
    int l = threadIdx.x;  // 64 threads, 1 block
    uint32_t hi = ei[2 * l + 1];
    int ei64 = __all(hi == 0u);

    uint32_t maxb = 0;
    int bf = 0, f16 = 0, hib = 0;
    for (int i = 0; i < 4; ++i) {
        uint32_t w = m1[l * 4 + i];
        uint32_t b0 = w & 0xffu, b1 = (w >> 8) & 0xffu,
                 b2 = (w >> 16) & 0xffu, b3 = (w >> 24) & 0xffu;
        uint32_t mb = b0 > b1 ? b0 : b1;
        uint32_t mb2 = b2 > b3 ? b2 : b3;
        mb = mb > mb2 ? mb : mb2;
        maxb = maxb > mb ? maxb : mb;
        if ((w & 0xffffu) == 0x3f80u) bf = 1;   // low half == 1.0 bf16
        if ((w & 0xffffu) == 0x3c00u) f16 = 1;  // low half == 1.0 f16
        if ((b1 | b2 | b3) != 0u) hib = 1;
    }
    int small  = __all(maxb <= 1u);
    int anybf  = __any(bf);
    int anyf16 = __any(f16);
    int anyhib = __any(hib);
    if (l == 0) {
        flags[0] = ei64;
        int mm;
        if (small)                 mm = anyhib ? 3 : 4;  // u8 vs i32
        else if (anybf || anyf16)  mm = 0;               // 16-bit
        else                       mm = 2;               // f32
        flags[1] = mm;
    }
}

__device__ __forceinline__ float mask_at(const void* p, int mode, long idx) {
    if (mode == 0) return ((const uint16_t*)p)[idx] ? 2.0f : 0.0f;
    if (mode == 2) return ((const float*)p)[idx] != 0.0f ? 2.0f : 0.0f;
    if (mode == 3) return ((const uint8_t*)p)[idx] ? 2.0f : 0.0f;
    return ((const int*)p)[idx] ? 2.0f : 0.0f;
}

__device__ __forceinline__ void load_edge(const int* p32, int mode64, long e,
                                          int& s, int& d) {
    if (mode64) { s = p32[2 * e]; d = p32[2 * (N_EDGES + e)]; }
    else        { s = p32[e];     d = p32[N_EDGES + e]; }
}

// ---------------- CSR build: histogram ----------------
__global__ __launch_bounds__(256) void k_hist(const void* __restrict__ ei,
                                              uint32_t* __restrict__ deg,
                                              const int* __restrict__ flags) {
    const int mode64 = flags[0];
    const int* p32 = (const int*)ei;
    for (long e = (long)blockIdx.x * 256 + threadIdx.x; e < N_EDGES;
         e += (long)gridDim.x * 256) {
        int s, d; load_edge(p32, mode64, e, s, d);
        atomicAdd(&deg[d], 1u);
    }
}

// ---------------- CSR build: scan (3 kernels) ----------------
__global__ __launch_bounds__(256) void k_scanA(const uint32_t* __restrict__ deg,
                                               uint32_t* __restrict__ partials) {
    __shared__ uint32_t sbuf[256];
    int idx = blockIdx.x * 256 + threadIdx.x;
    uint32_t v = idx < N_NODES ? deg[idx] : 0u;
    sbuf[threadIdx.x] = v;
    __syncthreads();
    for (int off = 128; off > 0; off >>= 1) {
        if (threadIdx.x < off) sbuf[threadIdx.x] += sbuf[threadIdx.x + off];
        __syncthreads();
    }
    if (threadIdx.x == 0) partials[blockIdx.x] = sbuf[0];
}

__global__ void k_scanB(uint32_t* __restrict__ partials,
                        uint32_t* __restrict__ poff,
                        uint32_t* __restrict__ starts) {
    if (threadIdx.x == 0) {
        uint32_t run = 0;
        for (int b = 0; b < SCAN_NB; ++b) {
            poff[b] = run;
            run += partials[b];
        }
        starts[N_NODES] = run;  // == N_EDGES
    }
}

__global__ __launch_bounds__(256) void k_scanC(const uint32_t* __restrict__ deg,
                                               const uint32_t* __restrict__ poff,
                                               uint32_t* __restrict__ starts) {
    __shared__ uint32_t sbuf[256];
    int idx = blockIdx.x * 256 + threadIdx.x;
    uint32_t v = idx < N_NODES ? deg[idx] : 0u;
    sbuf[threadIdx.x] = v;
    __syncthreads();
    // inclusive Hillis-Steele scan
    for (int off = 1; off < 256; off <<= 1) {
        uint32_t add = threadIdx.x >= off ? sbuf[threadIdx.x - off] : 0u;
        __syncthreads();
        sbuf[threadIdx.x] += add;
        __syncthreads();
    }
    if (idx < N_NODES) starts[idx] = poff[blockIdx.x] + sbuf[threadIdx.x] - v;
}

// ---------------- CSR build: reorder edges by dst ----------------
__global__ __launch_bounds__(256) void k_reorder(const void* __restrict__ ei,
                                                 const float* __restrict__ ew,
                                                 uint32_t* __restrict__ cursors,
                                                 int2* __restrict__ sorted,
                                                 const int* __restrict__ flags) {
    const int mode64 = flags[0];
    const int* p32 = (const int*)ei;
    for (long e = (long)blockIdx.x * 256 + threadIdx.x; e < N_EDGES;
         e += (long)gridDim.x * 256) {
        int s, d; load_edge(p32, mode64, e, s, d);
        float w = ew[e];
        uint32_t pos = atomicAdd(&cursors[d], 1u);
        sorted[pos] = make_int2(s, __float_as_int(w));
    }
}

// ---------------- CSR gather-aggregate: dest[n] = bias + sum_e H[src_e]*w_e ----
// one wave per node, lane = column
__global__ __launch_bounds__(256) void k_agg(const float* __restrict__ Hsrc,
                                             const int2* __restrict__ sorted,
                                             const uint32_t* __restrict__ starts,
                                             const float* __restrict__ bias,
                                             float* __restrict__ dest) {
    const int lane = threadIdx.x & 63;
    const long n = (long)blockIdx.x * 4 + (threadIdx.x >> 6);
    if (n >= N_NODES) return;
    uint32_t e  = starts[n];
    uint32_t e1 = starts[n + 1];
    float acc = bias ? bias[lane] : 0.0f;
    // 2x unroll for load-latency overlap
    for (; e + 2 <= e1; e += 2) {
        int2 p0 = sorted[e];
        int2 p1 = sorted[e + 1];
        float v0 = Hsrc[(long)p0.x * 64 + lane];
        float v1 = Hsrc[(long)p1.x * 64 + lane];
        acc = fmaf(v0, __int_as_float(p0.y), acc);
        acc = fmaf(v1, __int_as_float(p1.y), acc);
    }
    if (e < e1) {
        int2 p0 = sorted[e];
        acc = fmaf(Hsrc[(long)p0.x * 64 + lane], __int_as_float(p0.y), acc);
    }
    dest[n * 64 + lane] = acc;
}

// ---------------- GEMM1: H = (x .* m1 * 2) @ W1  [N,384]x[384,64] ----------------
__global__ __launch_bounds__(256) void k1_gemm(
        const float* __restrict__ x, const void* __restrict__ m1,
        const float* __restrict__ W1, float* __restrict__ H,
        const int* __restrict__ flags) {
    __shared__ float xm[32][IN_DIM];
    const int mmode = flags[1];
    const int node0 = blockIdx.x * 32;

    for (int i = threadIdx.x; i < 32 * (IN_DIM / 4); i += 256) {
        int r = i / (IN_DIM / 4), c4 = i % (IN_DIM / 4);
        long n = node0 + r;
        float4 v = ((const float4*)x)[n * (IN_DIM / 4) + c4];
        long base = n * IN_DIM + c4 * 4;
        float4 msk;
        if (mmode == 0) {
            ushort4 mu = ((const ushort4*)m1)[n * (IN_DIM / 4) + c4];
            msk.x = mu.x ? 2.0f : 0.0f; msk.y = mu.y ? 2.0f : 0.0f;
            msk.z = mu.z ? 2.0f : 0.0f; msk.w = mu.w ? 2.0f : 0.0f;
        } else {
            msk.x = mask_at(m1, mmode, base + 0);
            msk.y = mask_at(m1, mmode, base + 1);
            msk.z = mask_at(m1, mmode, base + 2);
            msk.w = mask_at(m1, mmode, base + 3);
        }
        v.x *= msk.x; v.y *= msk.y; v.z *= msk.z; v.w *= msk.w;
        *(float4*)&xm[r][c4 * 4] = v;
    }
    __syncthreads();

    const int c = threadIdx.x & 63;
    const int g = threadIdx.x >> 6;
    float acc[8];
#pragma unroll
    for (int r = 0; r < 8; ++r) acc[r] = 0.0f;

    for (int k = 0; k < IN_DIM; k += 4) {
        float w0 = W1[(k + 0) * 64 + c];
        float w1 = W1[(k + 1) * 64 + c];
        float w2 = W1[(k + 2) * 64 + c];
        float w3 = W1[(k + 3) * 64 + c];
#pragma unroll
        for (int r = 0; r < 8; ++r) {
            float4 xv = *(const float4*)&xm[g * 8 + r][k];
            acc[r] = fmaf(xv.x, w0, acc[r]);
            acc[r] = fmaf(xv.y, w1, acc[r]);
            acc[r] = fmaf(xv.z, w2, acc[r]);
            acc[r] = fmaf(xv.w, w3, acc[r]);
        }
    }
#pragma unroll
    for (int r = 0; r < 8; ++r)
        H[(long)(node0 + g * 8 + r) * 64 + c] = acc[r];
}

// ---------------- fallback atomic scatter ----------------
__global__ __launch_bounds__(256) void k_scatter(
        const float* __restrict__ Hsrc, const void* __restrict__ ei,
        const float* __restrict__ ew, float* __restrict__ dest,
        const int* __restrict__ flags) {
    const int mode64 = flags[0];
    const int lane = threadIdx.x & 63;
    const long wid = (long)blockIdx.x * 4 + (threadIdx.x >> 6);
    const long nw = (long)gridDim.x * 4;
    const int* p32 = (const int*)ei;
    for (long e = wid; e < N_EDGES; e += nw) {
        int s, d; load_edge(p32, mode64, e, s, d);
        float w = ew[e];
        float v = Hsrc[(long)s * 64 + lane] * w;
        atomicAdd(&dest[(long)d * 64 + lane], v);
    }
}

// ---------------- fused relu/dropout/GEMM2 ----------------
__global__ __launch_bounds__(256) void k3_mlp(
        const float* __restrict__ agg, const float* __restrict__ b1,
        const void* __restrict__ m2, const float* __restrict__ W2,
        float* __restrict__ H2, const int* __restrict__ flags) {
    __shared__ float w2s[64 * 64];
    __shared__ float vbuf[4][64];
    const int mmode = flags[1];
    for (int i = threadIdx.x; i < 4096; i += 256) w2s[i] = W2[i];
    __syncthreads();

    const int lane = threadIdx.x & 63;
    const int w = threadIdx.x >> 6;
    const float bc = b1[lane];
    const long wid = (long)blockIdx.x * 4 + w;
    const long nw = (long)gridDim.x * 4;
    for (long n = wid; n < N_NODES; n += nw) {
        float u = agg[n * 64 + lane] + bc;
        u = u > 0.0f ? u : 0.0f;
        u *= mask_at(m2, mmode, n * 64 + lane);
        vbuf[w][lane] = u;
        float acc = 0.0f;
#pragma unroll
        for (int j = 0; j < 64; j += 4) {
            float4 v4 = *(const float4*)&vbuf[w][j];
            acc = fmaf(v4.x, w2s[(j + 0) * 64 + lane], acc);
            acc = fmaf(v4.y, w2s[(j + 1) * 64 + lane], acc);
            acc = fmaf(v4.z, w2s[(j + 2) * 64 + lane], acc);
            acc = fmaf(v4.w, w2s[(j + 3) * 64 + lane], acc);
        }
        H2[n * 64 + lane] = acc;
    }
}

__global__ void k_init_out(float* __restrict__ out, const float* __restrict__ b2) {
    const long total = (long)N_NODES * 16;
    for (long j = (long)blockIdx.x * 256 + threadIdx.x; j < total;
         j += (long)gridDim.x * 256) {
        ((float4*)out)[j] = ((const float4*)b2)[j & 15];
    }
}

extern "C" void kernel_launch(void* const* d_in, const int* in_sizes, int n_in,
                              void* d_out, int out_size, void* d_ws, size_t ws_size,
                              hipStream_t stream) {
    const float* x  = (const float*)d_in[0];
    const void*  ei = d_in[1];
    const float* ew = (const float*)d_in[2];
    const float* W1 = (const float*)d_in[3];
    const float* b1 = (const float*)d_in[4];
    const float* W2 = (const float*)d_in[5];
    const float* b2 = (const float*)d_in[6];
    const void*  m1 = d_in[7];
    const void*  m2 = d_in[8];
    float* out = (float*)d_out;

    char* ws = (char*)d_ws;
    size_t off = 0;
    auto alloc = [&](size_t bytes) {
        char* p = ws + off;
        off += (bytes + 255) & ~(size_t)255;
        return p;
    };
    int*      flags   = (int*)alloc(32);
    float*    H       = (float*)alloc((size_t)N_NODES * 64 * 4);
    float*    AGG     = (float*)alloc((size_t)N_NODES * 64 * 4);
    int2*     sorted  = (int2*)alloc((size_t)N_EDGES * 8);
    uint32_t* starts  = (uint32_t*)alloc((size_t)(N_NODES + 1) * 4);
    uint32_t* deg     = (uint32_t*)alloc((size_t)N_NODES * 4);
    uint32_t* cursors = (uint32_t*)alloc((size_t)N_NODES * 4);
    uint32_t* poff    = (uint32_t*)alloc((size_t)SCAN_NB * 4);
    size_t need = off;

    hipLaunchKernelGGL(k_detect, dim3(1), dim3(64), 0, stream,
                       (const uint32_t*)ei, (const uint32_t*)m1, flags);

    if (ws_size >= need) {
        // --- CSR path ---
        hipMemsetAsync(deg, 0, (size_t)N_NODES * 4, stream);
        hipLaunchKernelGGL(k_hist, dim3(2048), dim3(256), 0, stream,
                           ei, deg, flags);
        hipLaunchKernelGGL(k_scanA, dim3(SCAN_NB), dim3(256), 0, stream,
                           deg, poff);  // poff used as partials temp
        hipLaunchKernelGGL(k_scanB, dim3(1), dim3(64), 0, stream,
                           poff, cursors, starts);  // cursors used as poff temp
        hipLaunchKernelGGL(k_scanC, dim3(SCAN_NB), dim3(256), 0, stream,
                           deg, cursors, starts);
        hipMemcpyAsync(cursors, starts, (size_t)N_NODES * 4,
                       hipMemcpyDeviceToDevice, stream);
        hipLaunchKernelGGL(k_reorder, dim3(2048), dim3(256), 0, stream,
                           ei, ew, cursors, sorted, flags);
        hipLaunchKernelGGL(k1_gemm, dim3(N_NODES / 32), dim3(256), 0, stream,
                           x, m1, W1, H, flags);
        hipLaunchKernelGGL(k_agg, dim3((N_NODES + 3) / 4), dim3(256), 0, stream,
                           H, sorted, starts, (const float*)nullptr, AGG);
        hipLaunchKernelGGL(k3_mlp, dim3(1024), dim3(256), 0, stream,
                           AGG, b1, m2, W2, H, flags);
        hipLaunchKernelGGL(k_agg, dim3((N_NODES + 3) / 4), dim3(256), 0, stream,
                           H, sorted, starts, b2, out);
    } else {
        // --- fallback: atomic path (round-1 structure) ---
        hipMemsetAsync(AGG, 0, (size_t)N_NODES * 64 * 4, stream);
        hipLaunchKernelGGL(k1_gemm, dim3(N_NODES / 32), dim3(256), 0, stream,
                           x, m1, W1, H, flags);
        hipLaunchKernelGGL(k_scatter, dim3(4096), dim3(256), 0, stream,
                           H, ei, ew, AGG, flags);
        hipLaunchKernelGGL(k3_mlp, dim3(1024), dim3(256), 0, stream,
                           AGG, b1, m2, W2, H, flags);
        hipLaunchKernelGGL(k_init_out, dim3(2048), dim3(256), 0, stream, out, b2);
        hipLaunchKernelGGL(k_scatter, dim3(4096), dim3(256), 0, stream,
                           H, ei, ew, out, flags);
    }
}

// Round 3
// 834.737 us; speedup vs baseline: 1.4950x; 1.1637x over previous
//
#include <hip/hip_runtime.h>
#include <hip/hip_bf16.h>
#include <stdint.h>

#define N_NODES 100000
#define N_EDGES 1600000
#define IN_DIM  384
#define HID_DIM 64
#define SCAN_NB 391   // ceil(100000/256)

typedef __attribute__((ext_vector_type(8))) short short8_t;
typedef __attribute__((ext_vector_type(4))) float f32x4;

// ---------------- runtime dtype detection ----------------
// flags[0]: edge_index is int64 (1) or int32 (0)
// flags[1]: mask mode: 0 = 16-bit (bf16/f16), 2 = f32, 3 = u8, 4 = i32
__global__ void k_detect(const uint32_t* __restrict__ ei,
                         const uint32_t* __restrict__ m1,
                         int* __restrict__ flags) {
    int l = threadIdx.x;  // 64 threads, 1 block
    uint32_t hi = ei[2 * l + 1];
    int ei64 = __all(hi == 0u);

    uint32_t maxb = 0;
    int bf = 0, f16 = 0, hib = 0;
    for (int i = 0; i < 4; ++i) {
        uint32_t w = m1[l * 4 + i];
        uint32_t b0 = w & 0xffu, b1 = (w >> 8) & 0xffu,
                 b2 = (w >> 16) & 0xffu, b3 = (w >> 24) & 0xffu;
        uint32_t mb = b0 > b1 ? b0 : b1;
        uint32_t mb2 = b2 > b3 ? b2 : b3;
        mb = mb > mb2 ? mb : mb2;
        maxb = maxb > mb ? maxb : mb;
        if ((w & 0xffffu) == 0x3f80u) bf = 1;
        if ((w & 0xffffu) == 0x3c00u) f16 = 1;
        if ((b1 | b2 | b3) != 0u) hib = 1;
    }
    int small  = __all(maxb <= 1u);
    int anybf  = __any(bf);
    int anyf16 = __any(f16);
    int anyhib = __any(hib);
    if (l == 0) {
        flags[0] = ei64;
        int mm;
        if (small)                 mm = anyhib ? 3 : 4;
        else if (anybf || anyf16)  mm = 0;
        else                       mm = 2;
        flags[1] = mm;
    }
}

__device__ __forceinline__ float mask_at(const void* p, int mode, long idx) {
    if (mode == 0) return ((const uint16_t*)p)[idx] ? 2.0f : 0.0f;
    if (mode == 2) return ((const float*)p)[idx] != 0.0f ? 2.0f : 0.0f;
    if (mode == 3) return ((const uint8_t*)p)[idx] ? 2.0f : 0.0f;
    return ((const int*)p)[idx] ? 2.0f : 0.0f;
}

__device__ __forceinline__ void load_edge(const int* p32, int mode64, long e,
                                          int& s, int& d) {
    if (mode64) { s = p32[2 * e]; d = p32[2 * (N_EDGES + e)]; }
    else        { s = p32[e];     d = p32[N_EDGES + e]; }
}

// f32 -> bf16 RNE, and back (bit ops: immune to header API drift)
__device__ __forceinline__ ushort f2bf(float f) {
    uint32_t u = __float_as_uint(f);
    return (ushort)((u + 0x7fffu + ((u >> 16) & 1u)) >> 16);
}
__device__ __forceinline__ float bf2f(ushort h) {
    return __uint_as_float(((uint32_t)h) << 16);
}

// ---------------- CSR build: histogram ----------------
__global__ __launch_bounds__(256) void k_hist(const void* __restrict__ ei,
                                              uint32_t* __restrict__ deg,
                                              const int* __restrict__ flags) {
    const int mode64 = flags[0];
    const int* p32 = (const int*)ei;
    for (long e = (long)blockIdx.x * 256 + threadIdx.x; e < N_EDGES;
         e += (long)gridDim.x * 256) {
        int s, d; load_edge(p32, mode64, e, s, d);
        atomicAdd(&deg[d], 1u);
    }
}

// ---------------- CSR build: scan (3 kernels) ----------------
__global__ __launch_bounds__(256) void k_scanA(const uint32_t* __restrict__ deg,
                                               uint32_t* __restrict__ partials) {
    __shared__ uint32_t sbuf[256];
    int idx = blockIdx.x * 256 + threadIdx.x;
    uint32_t v = idx < N_NODES ? deg[idx] : 0u;
    sbuf[threadIdx.x] = v;
    __syncthreads();
    for (int off = 128; off > 0; off >>= 1) {
        if (threadIdx.x < off) sbuf[threadIdx.x] += sbuf[threadIdx.x + off];
        __syncthreads();
    }
    if (threadIdx.x == 0) partials[blockIdx.x] = sbuf[0];
}

__global__ void k_scanB(uint32_t* __restrict__ partials,
                        uint32_t* __restrict__ poff,
                        uint32_t* __restrict__ starts) {
    if (threadIdx.x == 0) {
        uint32_t run = 0;
        for (int b = 0; b < SCAN_NB; ++b) {
            poff[b] = run;
            run += partials[b];
        }
        starts[N_NODES] = run;
    }
}

__global__ __launch_bounds__(256) void k_scanC(const uint32_t* __restrict__ deg,
                                               const uint32_t* __restrict__ poff,
                                               uint32_t* __restrict__ starts) {
    __shared__ uint32_t sbuf[256];
    int idx = blockIdx.x * 256 + threadIdx.x;
    uint32_t v = idx < N_NODES ? deg[idx] : 0u;
    sbuf[threadIdx.x] = v;
    __syncthreads();
    for (int off = 1; off < 256; off <<= 1) {
        uint32_t add = threadIdx.x >= off ? sbuf[threadIdx.x - off] : 0u;
        __syncthreads();
        sbuf[threadIdx.x] += add;
        __syncthreads();
    }
    if (idx < N_NODES) starts[idx] = poff[blockIdx.x] + sbuf[threadIdx.x] - v;
}

// ---------------- CSR build: reorder edges by dst ----------------
__global__ __launch_bounds__(256) void k_reorder(const void* __restrict__ ei,
                                                 const float* __restrict__ ew,
                                                 uint32_t* __restrict__ cursors,
                                                 int2* __restrict__ sorted,
                                                 const int* __restrict__ flags) {
    const int mode64 = flags[0];
    const int* p32 = (const int*)ei;
    for (long e = (long)blockIdx.x * 256 + threadIdx.x; e < N_EDGES;
         e += (long)gridDim.x * 256) {
        int s, d; load_edge(p32, mode64, e, s, d);
        float w = ew[e];
        uint32_t pos = atomicAdd(&cursors[d], 1u);
        sorted[pos] = make_int2(s, __float_as_int(w));
    }
}

// ---------------- GEMM1 via split-bf16 MFMA ----------------
// H = (x .* m1 * 2) @ W1, [100000x384]@[384x64], 3-pass hi/lo bf16 MFMA.
// Tile: 64 nodes x 64 cols, K-step 32. 256 threads = 4 waves; wave w owns
// rows [w*16, w*16+16), all 64 cols (4 N-tiles of 16).
__global__ __launch_bounds__(256) void k1_mfma(
        const float* __restrict__ x, const void* __restrict__ m1,
        const float* __restrict__ W1, float* __restrict__ H,
        const int* __restrict__ flags) {
    __shared__ ushort Ah[64][32];  // x hi  [node][k]
    __shared__ ushort Al[64][32];  // x lo
    __shared__ ushort Bh[64][32];  // W1^T hi [col][k]
    __shared__ ushort Bl[64][32];  // W1^T lo
    const int mmode = flags[1];
    const int t = threadIdx.x;
    const int node0 = blockIdx.x * 64;
    const int l = t & 63, w = t >> 6;

    f32x4 acc[4];
#pragma unroll
    for (int i = 0; i < 4; ++i) acc[i] = (f32x4)0.0f;

    const int arow = t >> 2;        // 0..63  (node row within tile)
    const int akq  = (t & 3) * 8;   // k offset within 32
    const int brow = t >> 3;        // 0..31  (k row of W chunk)
    const int bc0  = (t & 7) * 8;   // col offset

    for (int ks = 0; ks < IN_DIM; ks += 32) {
        // ---- stage A tile (masked, scaled, split hi/lo) ----
        {
            float xv[8];
            long node = node0 + arow;
            if (node < N_NODES) {
                long gb = node * IN_DIM + ks + akq;
                float4 x0 = *(const float4*)(x + gb);
                float4 x1 = *(const float4*)(x + gb + 4);
                xv[0] = x0.x; xv[1] = x0.y; xv[2] = x0.z; xv[3] = x0.w;
                xv[4] = x1.x; xv[5] = x1.y; xv[6] = x1.z; xv[7] = x1.w;
                float mv[8];
                if (mmode == 0) {
                    const ushort* mp = (const ushort*)m1 + gb;
                    ushort4 a = *(const ushort4*)mp;
                    ushort4 b = *(const ushort4*)(mp + 4);
                    mv[0] = a.x ? 2.f : 0.f; mv[1] = a.y ? 2.f : 0.f;
                    mv[2] = a.z ? 2.f : 0.f; mv[3] = a.w ? 2.f : 0.f;
                    mv[4] = b.x ? 2.f : 0.f; mv[5] = b.y ? 2.f : 0.f;
                    mv[6] = b.z ? 2.f : 0.f; mv[7] = b.w ? 2.f : 0.f;
                } else if (mmode == 2) {
                    const float* mp = (const float*)m1 + gb;
                    float4 a = *(const float4*)mp;
                    float4 b = *(const float4*)(mp + 4);
                    mv[0] = a.x != 0.f ? 2.f : 0.f; mv[1] = a.y != 0.f ? 2.f : 0.f;
                    mv[2] = a.z != 0.f ? 2.f : 0.f; mv[3] = a.w != 0.f ? 2.f : 0.f;
                    mv[4] = b.x != 0.f ? 2.f : 0.f; mv[5] = b.y != 0.f ? 2.f : 0.f;
                    mv[6] = b.z != 0.f ? 2.f : 0.f; mv[7] = b.w != 0.f ? 2.f : 0.f;
                } else if (mmode == 3) {
                    uint2 mb = *(const uint2*)((const uint8_t*)m1 + gb);
#pragma unroll
                    for (int j = 0; j < 4; ++j) {
                        mv[j]     = ((mb.x >> (8 * j)) & 0xffu) ? 2.f : 0.f;
                        mv[4 + j] = ((mb.y >> (8 * j)) & 0xffu) ? 2.f : 0.f;
                    }
                } else {
                    const int* mp = (const int*)m1 + gb;
                    int4 a = *(const int4*)mp;
                    int4 b = *(const int4*)(mp + 4);
                    mv[0] = a.x ? 2.f : 0.f; mv[1] = a.y ? 2.f : 0.f;
                    mv[2] = a.z ? 2.f : 0.f; mv[3] = a.w ? 2.f : 0.f;
                    mv[4] = b.x ? 2.f : 0.f; mv[5] = b.y ? 2.f : 0.f;
                    mv[6] = b.z ? 2.f : 0.f; mv[7] = b.w ? 2.f : 0.f;
                }
#pragma unroll
                for (int j = 0; j < 8; ++j) xv[j] *= mv[j];
            } else {
#pragma unroll
                for (int j = 0; j < 8; ++j) xv[j] = 0.0f;
            }
            uint ph[4], pl[4];
#pragma unroll
            for (int j2 = 0; j2 < 4; ++j2) {
                ushort h0 = f2bf(xv[2 * j2]);
                ushort h1 = f2bf(xv[2 * j2 + 1]);
                ushort l0 = f2bf(xv[2 * j2]     - bf2f(h0));
                ushort l1 = f2bf(xv[2 * j2 + 1] - bf2f(h1));
                ph[j2] = (uint)h0 | ((uint)h1 << 16);
                pl[j2] = (uint)l0 | ((uint)l1 << 16);
            }
            *(uint4*)&Ah[arow][akq] = make_uint4(ph[0], ph[1], ph[2], ph[3]);
            *(uint4*)&Al[arow][akq] = make_uint4(pl[0], pl[1], pl[2], pl[3]);
        }
        // ---- stage B tile (W1 chunk, transposed, split hi/lo) ----
        {
            long gb = (long)(ks + brow) * 64 + bc0;
            float4 w0 = *(const float4*)(W1 + gb);
            float4 w1 = *(const float4*)(W1 + gb + 4);
            float wv[8] = {w0.x, w0.y, w0.z, w0.w, w1.x, w1.y, w1.z, w1.w};
#pragma unroll
            for (int j = 0; j < 8; ++j) {
                ushort hs = f2bf(wv[j]);
                Bh[bc0 + j][brow] = hs;
                Bl[bc0 + j][brow] = f2bf(wv[j] - bf2f(hs));
            }
        }
        __syncthreads();
        // ---- fragments + MFMA ----
        short8_t ah = *(const short8_t*)&Ah[w * 16 + (l & 15)][(l >> 4) * 8];
        short8_t al = *(const short8_t*)&Al[w * 16 + (l & 15)][(l >> 4) * 8];
#pragma unroll
        for (int nt = 0; nt < 4; ++nt) {
            short8_t bh = *(const short8_t*)&Bh[nt * 16 + (l & 15)][(l >> 4) * 8];
            short8_t bl = *(const short8_t*)&Bl[nt * 16 + (l & 15)][(l >> 4) * 8];
            acc[nt] = __builtin_amdgcn_mfma_f32_16x16x32_bf16(ah, bh, acc[nt], 0, 0, 0);
            acc[nt] = __builtin_amdgcn_mfma_f32_16x16x32_bf16(ah, bl, acc[nt], 0, 0, 0);
            acc[nt] = __builtin_amdgcn_mfma_f32_16x16x32_bf16(al, bh, acc[nt], 0, 0, 0);
        }
        __syncthreads();
    }
    // ---- epilogue: C layout col=lane&15, row=(lane>>4)*4+reg ----
    const int r0 = (l >> 4) * 4;
#pragma unroll
    for (int nt = 0; nt < 4; ++nt) {
#pragma unroll
        for (int r = 0; r < 4; ++r) {
            long node = node0 + w * 16 + r0 + r;
            if (node < N_NODES) H[node * 64 + nt * 16 + (l & 15)] = acc[nt][r];
        }
    }
}

// ---------------- CSR gather-aggregate (plain): dest[n]=bias+sum H[src]*w ----
__global__ __launch_bounds__(256) void k_agg(const float* __restrict__ Hsrc,
                                             const int2* __restrict__ sorted,
                                             const uint32_t* __restrict__ starts,
                                             const float* __restrict__ bias,
                                             float* __restrict__ dest) {
    const int lane = threadIdx.x & 63;
    const long n = (long)blockIdx.x * 4 + (threadIdx.x >> 6);
    if (n >= N_NODES) return;
    uint32_t e  = starts[n];
    uint32_t e1 = starts[n + 1];
    float acc = bias ? bias[lane] : 0.0f;
    for (; e + 2 <= e1; e += 2) {
        int2 p0 = sorted[e];
        int2 p1 = sorted[e + 1];
        float v0 = Hsrc[(long)p0.x * 64 + lane];
        float v1 = Hsrc[(long)p1.x * 64 + lane];
        acc = fmaf(v0, __int_as_float(p0.y), acc);
        acc = fmaf(v1, __int_as_float(p1.y), acc);
    }
    if (e < e1) {
        int2 p0 = sorted[e];
        acc = fmaf(Hsrc[(long)p0.x * 64 + lane], __int_as_float(p0.y), acc);
    }
    dest[n * 64 + lane] = acc;
}

// ---------------- fused: agg1 + b1 + relu + mask2 + @W2 ----------------
// grid must be exactly N_NODES/4 blocks (one node per wave, no guard:
// barrier before node work requires all threads participate).
__global__ __launch_bounds__(256) void k_aggmlp(
        const float* __restrict__ Hsrc, const int2* __restrict__ sorted,
        const uint32_t* __restrict__ starts, const float* __restrict__ b1,
        const void* __restrict__ m2, const float* __restrict__ W2,
        float* __restrict__ H2, const int* __restrict__ flags) {
    __shared__ float w2s[64 * 64];
    __shared__ float vbuf[4][64];
    const int mmode = flags[1];
    for (int i = threadIdx.x; i < 4096; i += 256) w2s[i] = W2[i];
    __syncthreads();

    const int lane = threadIdx.x & 63;
    const int w = threadIdx.x >> 6;
    const long n = (long)blockIdx.x * 4 + w;  // < N_NODES by grid construction
    uint32_t e  = starts[n];
    uint32_t e1 = starts[n + 1];
    float acc = 0.0f;
    for (; e + 2 <= e1; e += 2) {
        int2 p0 = sorted[e];
        int2 p1 = sorted[e + 1];
        float v0 = Hsrc[(long)p0.x * 64 + lane];
        float v1 = Hsrc[(long)p1.x * 64 + lane];
        acc = fmaf(v0, __int_as_float(p0.y), acc);
        acc = fmaf(v1, __int_as_float(p1.y), acc);
    }
    if (e < e1) {
        int2 p0 = sorted[e];
        acc = fmaf(Hsrc[(long)p0.x * 64 + lane], __int_as_float(p0.y), acc);
    }
    float u = acc + b1[lane];
    u = u > 0.0f ? u : 0.0f;
    u *= mask_at(m2, mmode, n * 64 + lane);
    vbuf[w][lane] = u;  // wave-local: ds ops in-order, no barrier needed
    float h2 = 0.0f;
#pragma unroll
    for (int j = 0; j < 64; j += 4) {
        float4 v4 = *(const float4*)&vbuf[w][j];
        h2 = fmaf(v4.x, w2s[(j + 0) * 64 + lane], h2);
        h2 = fmaf(v4.y, w2s[(j + 1) * 64 + lane], h2);
        h2 = fmaf(v4.z, w2s[(j + 2) * 64 + lane], h2);
        h2 = fmaf(v4.w, w2s[(j + 3) * 64 + lane], h2);
    }
    H2[n * 64 + lane] = h2;
}

// ---------------- fallback atomic path kernels ----------------
__global__ __launch_bounds__(256) void k_scatter(
        const float* __restrict__ Hsrc, const void* __restrict__ ei,
        const float* __restrict__ ew, float* __restrict__ dest,
        const int* __restrict__ flags) {
    const int mode64 = flags[0];
    const int lane = threadIdx.x & 63;
    const long wid = (long)blockIdx.x * 4 + (threadIdx.x >> 6);
    const long nw = (long)gridDim.x * 4;
    const int* p32 = (const int*)ei;
    for (long e = wid; e < N_EDGES; e += nw) {
        int s, d; load_edge(p32, mode64, e, s, d);
        float w = ew[e];
        float v = Hsrc[(long)s * 64 + lane] * w;
        atomicAdd(&dest[(long)d * 64 + lane], v);
    }
}

__global__ __launch_bounds__(256) void k3_mlp(
        const float* __restrict__ agg, const float* __restrict__ b1,
        const void* __restrict__ m2, const float* __restrict__ W2,
        float* __restrict__ H2, const int* __restrict__ flags) {
    __shared__ float w2s[64 * 64];
    __shared__ float vbuf[4][64];
    const int mmode = flags[1];
    for (int i = threadIdx.x; i < 4096; i += 256) w2s[i] = W2[i];
    __syncthreads();
    const int lane = threadIdx.x & 63;
    const int w = threadIdx.x >> 6;
    const float bc = b1[lane];
    const long wid = (long)blockIdx.x * 4 + w;
    const long nw = (long)gridDim.x * 4;
    for (long n = wid; n < N_NODES; n += nw) {
        float u = agg[n * 64 + lane] + bc;
        u = u > 0.0f ? u : 0.0f;
        u *= mask_at(m2, mmode, n * 64 + lane);
        vbuf[w][lane] = u;
        float acc = 0.0f;
#pragma unroll
        for (int j = 0; j < 64; j += 4) {
            float4 v4 = *(const float4*)&vbuf[w][j];
            acc = fmaf(v4.x, w2s[(j + 0) * 64 + lane], acc);
            acc = fmaf(v4.y, w2s[(j + 1) * 64 + lane], acc);
            acc = fmaf(v4.z, w2s[(j + 2) * 64 + lane], acc);
            acc = fmaf(v4.w, w2s[(j + 3) * 64 + lane], acc);
        }
        H2[n * 64 + lane] = acc;
    }
}

__global__ void k_init_out(float* __restrict__ out, const float* __restrict__ b2) {
    const long total = (long)N_NODES * 16;
    for (long j = (long)blockIdx.x * 256 + threadIdx.x; j < total;
         j += (long)gridDim.x * 256) {
        ((float4*)out)[j] = ((const float4*)b2)[j & 15];
    }
}

extern "C" void kernel_launch(void* const* d_in, const int* in_sizes, int n_in,
                              void* d_out, int out_size, void* d_ws, size_t ws_size,
                              hipStream_t stream) {
    const float* x  = (const float*)d_in[0];
    const void*  ei = d_in[1];
    const float* ew = (const float*)d_in[2];
    const float* W1 = (const float*)d_in[3];
    const float* b1 = (const float*)d_in[4];
    const float* W2 = (const float*)d_in[5];
    const float* b2 = (const float*)d_in[6];
    const void*  m1 = d_in[7];
    const void*  m2 = d_in[8];
    float* out = (float*)d_out;

    char* ws = (char*)d_ws;
    size_t off = 0;
    auto alloc = [&](size_t bytes) {
        char* p = ws + off;
        off += (bytes + 255) & ~(size_t)255;
        return p;
    };
    int*      flags   = (int*)alloc(32);
    float*    H       = (float*)alloc((size_t)N_NODES * 64 * 4);
    float*    AGG     = (float*)alloc((size_t)N_NODES * 64 * 4);
    int2*     sorted  = (int2*)alloc((size_t)N_EDGES * 8);
    uint32_t* starts  = (uint32_t*)alloc((size_t)(N_NODES + 1) * 4);
    uint32_t* deg     = (uint32_t*)alloc((size_t)N_NODES * 4);
    uint32_t* cursors = (uint32_t*)alloc((size_t)N_NODES * 4);
    uint32_t* poff    = (uint32_t*)alloc((size_t)SCAN_NB * 4);
    size_t need = off;

    hipLaunchKernelGGL(k_detect, dim3(1), dim3(64), 0, stream,
                       (const uint32_t*)ei, (const uint32_t*)m1, flags);

    if (ws_size >= need) {
        // --- CSR path ---
        hipMemsetAsync(deg, 0, (size_t)N_NODES * 4, stream);
        hipLaunchKernelGGL(k_hist, dim3(2048), dim3(256), 0, stream,
                           ei, deg, flags);
        hipLaunchKernelGGL(k_scanA, dim3(SCAN_NB), dim3(256), 0, stream,
                           deg, poff);
        hipLaunchKernelGGL(k_scanB, dim3(1), dim3(64), 0, stream,
                           poff, cursors, starts);
        hipLaunchKernelGGL(k_scanC, dim3(SCAN_NB), dim3(256), 0, stream,
                           deg, cursors, starts);
        hipMemcpyAsync(cursors, starts, (size_t)N_NODES * 4,
                       hipMemcpyDeviceToDevice, stream);
        hipLaunchKernelGGL(k_reorder, dim3(2048), dim3(256), 0, stream,
                           ei, ew, cursors, sorted, flags);
        hipLaunchKernelGGL(k1_mfma, dim3((N_NODES + 63) / 64), dim3(256), 0, stream,
                           x, m1, W1, H, flags);
        hipLaunchKernelGGL(k_aggmlp, dim3(N_NODES / 4), dim3(256), 0, stream,
                           H, sorted, starts, b1, m2, W2, AGG, flags);
        hipLaunchKernelGGL(k_agg, dim3(N_NODES / 4), dim3(256), 0, stream,
                           AGG, sorted, starts, b2, out);
    } else {
        // --- fallback: atomic path ---
        hipMemsetAsync(AGG, 0, (size_t)N_NODES * 64 * 4, stream);
        hipLaunchKernelGGL(k1_mfma, dim3((N_NODES + 63) / 64), dim3(256), 0, stream,
                           x, m1, W1, H, flags);
        hipLaunchKernelGGL(k_scatter, dim3(4096), dim3(256), 0, stream,
                           H, ei, ew, AGG, flags);
        hipLaunchKernelGGL(k3_mlp, dim3(1024), dim3(256), 0, stream,
                           AGG, b1, m2, W2, H, flags);
        hipLaunchKernelGGL(k_init_out, dim3(2048), dim3(256), 0, stream, out, b2);
        hipLaunchKernelGGL(k_scatter, dim3(4096), dim3(256), 0, stream,
                           H, ei, ew, out, flags);
    }
}

// Round 5
// 785.313 us; speedup vs baseline: 1.5891x; 1.0629x over previous
//
#include <hip/hip_runtime.h>
#include <hip/hip_bf16.h>
#include <stdint.h>

#define N_NODES 100000
#define N_EDGES 1600000
#define IN_DIM  384
#define HID_DIM 64
#define SCAN_NB 391   // ceil(100000/256)

typedef __attribute__((ext_vector_type(8))) short short8_t;
typedef __attribute__((ext_vector_type(4))) float f32x4;

// ---------------- runtime dtype detection ----------------
// flags[0]: edge_index is int64 (1) or int32 (0)
// flags[1]: mask mode: 0 = 16-bit (bf16/f16), 2 = f32, 3 = u8, 4 = i32
__global__ void k_detect(const uint32_t* __restrict__ ei,
                         const uint32_t* __restrict__ m1,
                         int* __restrict__ flags) {
    int l = threadIdx.x;  // 64 threads, 1 block
    uint32_t hi = ei[2 * l + 1];
    int ei64 = __all(hi == 0u);

    uint32_t maxb = 0;
    int bf = 0, f16 = 0, hib = 0;
    for (int i = 0; i < 4; ++i) {
        uint32_t w = m1[l * 4 + i];
        uint32_t b0 = w & 0xffu, b1 = (w >> 8) & 0xffu,
                 b2 = (w >> 16) & 0xffu, b3 = (w >> 24) & 0xffu;
        uint32_t mb = b0 > b1 ? b0 : b1;
        uint32_t mb2 = b2 > b3 ? b2 : b3;
        mb = mb > mb2 ? mb : mb2;
        maxb = maxb > mb ? maxb : mb;
        if ((w & 0xffffu) == 0x3f80u) bf = 1;
        if ((w & 0xffffu) == 0x3c00u) f16 = 1;
        if ((b1 | b2 | b3) != 0u) hib = 1;
    }
    int small  = __all(maxb <= 1u);
    int anybf  = __any(bf);
    int anyf16 = __any(f16);
    int anyhib = __any(hib);
    if (l == 0) {
        flags[0] = ei64;
        int mm;
        if (small)                 mm = anyhib ? 3 : 4;
        else if (anybf || anyf16)  mm = 0;
        else                       mm = 2;
        flags[1] = mm;
    }
}

__device__ __forceinline__ float mask_at(const void* p, int mode, long idx) {
    if (mode == 0) return ((const uint16_t*)p)[idx] ? 2.0f : 0.0f;
    if (mode == 2) return ((const float*)p)[idx] != 0.0f ? 2.0f : 0.0f;
    if (mode == 3) return ((const uint8_t*)p)[idx] ? 2.0f : 0.0f;
    return ((const int*)p)[idx] ? 2.0f : 0.0f;
}

__device__ __forceinline__ void load_edge(const int* p32, int mode64, long e,
                                          int& s, int& d) {
    if (mode64) { s = p32[2 * e]; d = p32[2 * (N_EDGES + e)]; }
    else        { s = p32[e];     d = p32[N_EDGES + e]; }
}

// f32 -> bf16 RNE, and back
__device__ __forceinline__ ushort f2bf(float f) {
    uint32_t u = __float_as_uint(f);
    return (ushort)((u + 0x7fffu + ((u >> 16) & 1u)) >> 16);
}
__device__ __forceinline__ float bf2f(ushort h) {
    return __uint_as_float(((uint32_t)h) << 16);
}

// ---------------- CSR build: histogram ----------------
__global__ __launch_bounds__(256) void k_hist(const void* __restrict__ ei,
                                              uint32_t* __restrict__ deg,
                                              const int* __restrict__ flags) {
    const int mode64 = flags[0];
    const int* p32 = (const int*)ei;
    for (long e = (long)blockIdx.x * 256 + threadIdx.x; e < N_EDGES;
         e += (long)gridDim.x * 256) {
        int s, d; load_edge(p32, mode64, e, s, d);
        atomicAdd(&deg[d], 1u);
    }
}

// ---------------- CSR build: scan ----------------
__global__ __launch_bounds__(256) void k_scanA(const uint32_t* __restrict__ deg,
                                               uint32_t* __restrict__ partials) {
    __shared__ uint32_t sbuf[256];
    int idx = blockIdx.x * 256 + threadIdx.x;
    uint32_t v = idx < N_NODES ? deg[idx] : 0u;
    sbuf[threadIdx.x] = v;
    __syncthreads();
    for (int off = 128; off > 0; off >>= 1) {
        if (threadIdx.x < off) sbuf[threadIdx.x] += sbuf[threadIdx.x + off];
        __syncthreads();
    }
    if (threadIdx.x == 0) partials[blockIdx.x] = sbuf[0];
}

// parallel scan of block partials (one 512-thread block)
__global__ __launch_bounds__(512) void k_scanB(const uint32_t* __restrict__ partials,
                                               uint32_t* __restrict__ poff,
                                               uint32_t* __restrict__ starts) {
    __shared__ uint32_t sbuf[512];
    int t = threadIdx.x;
    uint32_t v = t < SCAN_NB ? partials[t] : 0u;
    sbuf[t] = v;
    __syncthreads();
    for (int off = 1; off < 512; off <<= 1) {
        uint32_t add = t >= off ? sbuf[t - off] : 0u;
        __syncthreads();
        sbuf[t] += add;
        __syncthreads();
    }
    if (t < SCAN_NB) poff[t] = sbuf[t] - v;           // exclusive
    if (t == SCAN_NB - 1) starts[N_NODES] = sbuf[t];  // total
}

__global__ __launch_bounds__(256) void k_scanC(const uint32_t* __restrict__ deg,
                                               const uint32_t* __restrict__ poff,
                                               uint32_t* __restrict__ starts) {
    __shared__ uint32_t sbuf[256];
    int idx = blockIdx.x * 256 + threadIdx.x;
    uint32_t v = idx < N_NODES ? deg[idx] : 0u;
    sbuf[threadIdx.x] = v;
    __syncthreads();
    for (int off = 1; off < 256; off <<= 1) {
        uint32_t add = threadIdx.x >= off ? sbuf[threadIdx.x - off] : 0u;
        __syncthreads();
        sbuf[threadIdx.x] += add;
        __syncthreads();
    }
    if (idx < N_NODES) starts[idx] = poff[blockIdx.x] + sbuf[threadIdx.x] - v;
}

// ---------------- CSR build: reorder edges by dst ----------------
__global__ __launch_bounds__(256) void k_reorder(const void* __restrict__ ei,
                                                 const float* __restrict__ ew,
                                                 uint32_t* __restrict__ cursors,
                                                 int2* __restrict__ sorted,
                                                 const int* __restrict__ flags) {
    const int mode64 = flags[0];
    const int* p32 = (const int*)ei;
    for (long e = (long)blockIdx.x * 256 + threadIdx.x; e < N_EDGES;
         e += (long)gridDim.x * 256) {
        int s, d; load_edge(p32, mode64, e, s, d);
        float w = ew[e];
        uint32_t pos = atomicAdd(&cursors[d], 1u);
        sorted[pos] = make_int2(s, __float_as_int(w));
    }
}

// ---------------- pre-pack W1 into bf16 hi/lo B-fragments ----------------
// Wpack[(8*ks + pass*4 + nt)*64 + l][8]: lane l, j -> W1[ks*32+(l>>4)*8+j][nt*16+(l&15)]
__global__ __launch_bounds__(256) void k_packW(const float* __restrict__ W1,
                                               ushort* __restrict__ Wpack) {
    const int ks = blockIdx.x;        // 0..11
    const int t  = threadIdx.x;
    const int nt = t >> 6, l = t & 63;
    ushort hs[8], ls[8];
#pragma unroll
    for (int j = 0; j < 8; ++j) {
        float wv = W1[(ks * 32 + (l >> 4) * 8 + j) * 64 + nt * 16 + (l & 15)];
        ushort h = f2bf(wv);
        hs[j] = h;
        ls[j] = f2bf(wv - bf2f(h));
    }
    *(short8_t*)&Wpack[((8 * ks + nt) * 64 + l) * 8]     = *(short8_t*)hs;
    *(short8_t*)&Wpack[((8 * ks + 4 + nt) * 64 + l) * 8] = *(short8_t*)ls;
}

// ---------------- GEMM1: H = bf16((x .* m1 * 2) @ W1), no LDS ----------------
// 256 thr = 4 waves; wave w owns rows node0 + w*16 + (l&15), all 64 cols.
__global__ __launch_bounds__(256) void k1_mfma(
        const float* __restrict__ x, const void* __restrict__ m1,
        const ushort* __restrict__ Wpack, ushort* __restrict__ Hb,
        const int* __restrict__ flags) {
    const int mmode = flags[1];
    const int t = threadIdx.x;
    const int l = t & 63, w = t >> 6;
    const int node0 = blockIdx.x * 64;
    const long row = node0 + w * 16 + (l & 15);
    const int kq = (l >> 4) * 8;
    const bool valid = row < N_NODES;

    f32x4 acc[4];
#pragma unroll
    for (int i = 0; i < 4; ++i) acc[i] = (f32x4)0.0f;

    for (int ks = 0; ks < 12; ++ks) {
        // ---- A-fragment direct from global ----
        float xv[8];
        if (valid) {
            long gb = row * IN_DIM + ks * 32 + kq;
            float4 x0 = *(const float4*)(x + gb);
            float4 x1 = *(const float4*)(x + gb + 4);
            xv[0] = x0.x; xv[1] = x0.y; xv[2] = x0.z; xv[3] = x0.w;
            xv[4] = x1.x; xv[5] = x1.y; xv[6] = x1.z; xv[7] = x1.w;
            float mv[8];
            if (mmode == 0) {
                const ushort* mp = (const ushort*)m1 + gb;
                ushort4 a = *(const ushort4*)mp;
                ushort4 b = *(const ushort4*)(mp + 4);
                mv[0] = a.x ? 2.f : 0.f; mv[1] = a.y ? 2.f : 0.f;
                mv[2] = a.z ? 2.f : 0.f; mv[3] = a.w ? 2.f : 0.f;
                mv[4] = b.x ? 2.f : 0.f; mv[5] = b.y ? 2.f : 0.f;
                mv[6] = b.z ? 2.f : 0.f; mv[7] = b.w ? 2.f : 0.f;
            } else if (mmode == 2) {
                const float* mp = (const float*)m1 + gb;
                float4 a = *(const float4*)mp;
                float4 b = *(const float4*)(mp + 4);
                mv[0] = a.x != 0.f ? 2.f : 0.f; mv[1] = a.y != 0.f ? 2.f : 0.f;
                mv[2] = a.z != 0.f ? 2.f : 0.f; mv[3] = a.w != 0.f ? 2.f : 0.f;
                mv[4] = b.x != 0.f ? 2.f : 0.f; mv[5] = b.y != 0.f ? 2.f : 0.f;
                mv[6] = b.z != 0.f ? 2.f : 0.f; mv[7] = b.w != 0.f ? 2.f : 0.f;
            } else if (mmode == 3) {
                uint2 mb = *(const uint2*)((const uint8_t*)m1 + gb);
#pragma unroll
                for (int j = 0; j < 4; ++j) {
                    mv[j]     = ((mb.x >> (8 * j)) & 0xffu) ? 2.f : 0.f;
                    mv[4 + j] = ((mb.y >> (8 * j)) & 0xffu) ? 2.f : 0.f;
                }
            } else {
                const int* mp = (const int*)m1 + gb;
                int4 a = *(const int4*)mp;
                int4 b = *(const int4*)(mp + 4);
                mv[0] = a.x ? 2.f : 0.f; mv[1] = a.y ? 2.f : 0.f;
                mv[2] = a.z ? 2.f : 0.f; mv[3] = a.w ? 2.f : 0.f;
                mv[4] = b.x ? 2.f : 0.f; mv[5] = b.y ? 2.f : 0.f;
                mv[6] = b.z ? 2.f : 0.f; mv[7] = b.w ? 2.f : 0.f;
            }
#pragma unroll
            for (int j = 0; j < 8; ++j) xv[j] *= mv[j];
        } else {
#pragma unroll
            for (int j = 0; j < 8; ++j) xv[j] = 0.0f;
        }
        ushort ap[8];
#pragma unroll
        for (int j = 0; j < 8; ++j) ap[j] = f2bf(xv[j]);
        short8_t ah = *(short8_t*)ap;

        // ---- B-fragments from prepacked global (L2-hot) + MFMA ----
#pragma unroll
        for (int nt = 0; nt < 4; ++nt) {
            short8_t bh = *(const short8_t*)&Wpack[((8 * ks + nt) * 64 + l) * 8];
            short8_t bl = *(const short8_t*)&Wpack[((8 * ks + 4 + nt) * 64 + l) * 8];
            acc[nt] = __builtin_amdgcn_mfma_f32_16x16x32_bf16(ah, bh, acc[nt], 0, 0, 0);
            acc[nt] = __builtin_amdgcn_mfma_f32_16x16x32_bf16(ah, bl, acc[nt], 0, 0, 0);
        }
    }
    // ---- epilogue: C layout col=lane&15, row=(lane>>4)*4+reg ----
    const int r0 = (l >> 4) * 4;
#pragma unroll
    for (int nt = 0; nt < 4; ++nt) {
#pragma unroll
        for (int r = 0; r < 4; ++r) {
            long node = node0 + w * 16 + r0 + r;
            if (node < N_NODES)
                Hb[node * 64 + nt * 16 + (l & 15)] = f2bf(acc[nt][r]);
        }
    }
}

// ---------------- fused: agg1(bf16 gather) + b1 + relu + mask2 + @W2 -> bf16 ----
// grid must be exactly N_NODES/4 blocks.
__global__ __launch_bounds__(256) void k_aggmlp(
        const ushort* __restrict__ Hb, const int2* __restrict__ sorted,
        const uint32_t* __restrict__ starts, const float* __restrict__ b1,
        const void* __restrict__ m2, const float* __restrict__ W2,
        ushort* __restrict__ H2b, const int* __restrict__ flags) {
    __shared__ float w2s[64 * 64];
    __shared__ float vbuf[4][64];
    const int mmode = flags[1];
    for (int i = threadIdx.x; i < 4096; i += 256) w2s[i] = W2[i];
    __syncthreads();

    const int lane = threadIdx.x & 63;
    const int w = threadIdx.x >> 6;
    const long n = (long)blockIdx.x * 4 + w;
    uint32_t e  = starts[n];
    uint32_t e1 = starts[n + 1];
    float acc = 0.0f;
    for (; e + 4 <= e1; e += 4) {
        int2 p0 = sorted[e],     p1 = sorted[e + 1];
        int2 p2 = sorted[e + 2], p3 = sorted[e + 3];
        float v0 = bf2f(Hb[(long)p0.x * 64 + lane]);
        float v1 = bf2f(Hb[(long)p1.x * 64 + lane]);
        float v2 = bf2f(Hb[(long)p2.x * 64 + lane]);
        float v3 = bf2f(Hb[(long)p3.x * 64 + lane]);
        acc = fmaf(v0, __int_as_float(p0.y), acc);
        acc = fmaf(v1, __int_as_float(p1.y), acc);
        acc = fmaf(v2, __int_as_float(p2.y), acc);
        acc = fmaf(v3, __int_as_float(p3.y), acc);
    }
    for (; e < e1; ++e) {
        int2 p0 = sorted[e];
        acc = fmaf(bf2f(Hb[(long)p0.x * 64 + lane]), __int_as_float(p0.y), acc);
    }
    float u = acc + b1[lane];
    u = u > 0.0f ? u : 0.0f;
    u *= mask_at(m2, mmode, n * 64 + lane);
    vbuf[w][lane] = u;  // wave-local LDS: in-order, no barrier needed
    float h2 = 0.0f;
#pragma unroll
    for (int j = 0; j < 64; j += 4) {
        float4 v4 = *(const float4*)&vbuf[w][j];
        h2 = fmaf(v4.x, w2s[(j + 0) * 64 + lane], h2);
        h2 = fmaf(v4.y, w2s[(j + 1) * 64 + lane], h2);
        h2 = fmaf(v4.z, w2s[(j + 2) * 64 + lane], h2);
        h2 = fmaf(v4.w, w2s[(j + 3) * 64 + lane], h2);
    }
    H2b[n * 64 + lane] = f2bf(h2);
}

// ---------------- final: out = b2 + agg2(bf16 gather), f32 out ----------------
__global__ __launch_bounds__(256) void k_agg(const ushort* __restrict__ Hb,
                                             const int2* __restrict__ sorted,
                                             const uint32_t* __restrict__ starts,
                                             const float* __restrict__ bias,
                                             float* __restrict__ dest) {
    const int lane = threadIdx.x & 63;
    const long n = (long)blockIdx.x * 4 + (threadIdx.x >> 6);
    if (n >= N_NODES) return;
    uint32_t e  = starts[n];
    uint32_t e1 = starts[n + 1];
    float acc = bias[lane];
    for (; e + 4 <= e1; e += 4) {
        int2 p0 = sorted[e],     p1 = sorted[e + 1];
        int2 p2 = sorted[e + 2], p3 = sorted[e + 3];
        float v0 = bf2f(Hb[(long)p0.x * 64 + lane]);
        float v1 = bf2f(Hb[(long)p1.x * 64 + lane]);
        float v2 = bf2f(Hb[(long)p2.x * 64 + lane]);
        float v3 = bf2f(Hb[(long)p3.x * 64 + lane]);
        acc = fmaf(v0, __int_as_float(p0.y), acc);
        acc = fmaf(v1, __int_as_float(p1.y), acc);
        acc = fmaf(v2, __int_as_float(p2.y), acc);
        acc = fmaf(v3, __int_as_float(p3.y), acc);
    }
    for (; e < e1; ++e) {
        int2 p0 = sorted[e];
        acc = fmaf(bf2f(Hb[(long)p0.x * 64 + lane]), __int_as_float(p0.y), acc);
    }
    dest[n * 64 + lane] = acc;
}

// ---------------- fallback atomic path ----------------
__global__ __launch_bounds__(256) void k_scatter(
        const ushort* __restrict__ Hb, const void* __restrict__ ei,
        const float* __restrict__ ew, float* __restrict__ dest,
        const int* __restrict__ flags) {
    const int mode64 = flags[0];
    const int lane = threadIdx.x & 63;
    const long wid = (long)blockIdx.x * 4 + (threadIdx.x >> 6);
    const long nw = (long)gridDim.x * 4;
    const int* p32 = (const int*)ei;
    for (long e = wid; e < N_EDGES; e += nw) {
        int s, d; load_edge(p32, mode64, e, s, d);
        float w = ew[e];
        float v = bf2f(Hb[(long)s * 64 + lane]) * w;
        atomicAdd(&dest[(long)d * 64 + lane], v);
    }
}

__global__ __launch_bounds__(256) void k3_mlp(
        const float* __restrict__ agg, const float* __restrict__ b1,
        const void* __restrict__ m2, const float* __restrict__ W2,
        ushort* __restrict__ H2b, const int* __restrict__ flags) {
    __shared__ float w2s[64 * 64];
    __shared__ float vbuf[4][64];
    const int mmode = flags[1];
    for (int i = threadIdx.x; i < 4096; i += 256) w2s[i] = W2[i];
    __syncthreads();
    const int lane = threadIdx.x & 63;
    const int w = threadIdx.x >> 6;
    const float bc = b1[lane];
    const long wid = (long)blockIdx.x * 4 + w;
    const long nw = (long)gridDim.x * 4;
    for (long n = wid; n < N_NODES; n += nw) {
        float u = agg[n * 64 + lane] + bc;
        u = u > 0.0f ? u : 0.0f;
        u *= mask_at(m2, mmode, n * 64 + lane);
        vbuf[w][lane] = u;
        float acc = 0.0f;
#pragma unroll
        for (int j = 0; j < 64; j += 4) {
            float4 v4 = *(const float4*)&vbuf[w][j];
            acc = fmaf(v4.x, w2s[(j + 0) * 64 + lane], acc);
            acc = fmaf(v4.y, w2s[(j + 1) * 64 + lane], acc);
            acc = fmaf(v4.z, w2s[(j + 2) * 64 + lane], acc);
            acc = fmaf(v4.w, w2s[(j + 3) * 64 + lane], acc);
        }
        H2b[n * 64 + lane] = f2bf(acc);
    }
}

__global__ void k_init_out(float* __restrict__ out, const float* __restrict__ b2) {
    const long total = (long)N_NODES * 16;
    for (long j = (long)blockIdx.x * 256 + threadIdx.x; j < total;
         j += (long)gridDim.x * 256) {
        ((float4*)out)[j] = ((const float4*)b2)[j & 15];
    }
}

extern "C" void kernel_launch(void* const* d_in, const int* in_sizes, int n_in,
                              void* d_out, int out_size, void* d_ws, size_t ws_size,
                              hipStream_t stream) {
    const float* x  = (const float*)d_in[0];
    const void*  ei = d_in[1];
    const float* ew = (const float*)d_in[2];
    const float* W1 = (const float*)d_in[3];
    const float* b1 = (const float*)d_in[4];
    const float* W2 = (const float*)d_in[5];
    const float* b2 = (const float*)d_in[6];
    const void*  m1 = d_in[7];
    const void*  m2 = d_in[8];
    float* out = (float*)d_out;

    char* ws = (char*)d_ws;
    size_t off = 0;
    auto alloc = [&](size_t bytes) {
        char* p = ws + off;
        off += (bytes + 255) & ~(size_t)255;
        return p;
    };
    int*      flags   = (int*)alloc(32);
    ushort*   Hb      = (ushort*)alloc((size_t)N_NODES * 64 * 2);
    ushort*   H2b     = (ushort*)alloc((size_t)N_NODES * 64 * 2);
    float*    AGG     = (float*)alloc((size_t)N_NODES * 64 * 4);   // fallback only
    int2*     sorted  = (int2*)alloc((size_t)N_EDGES * 8);
    uint32_t* starts  = (uint32_t*)alloc((size_t)(N_NODES + 1) * 4);
    uint32_t* deg     = (uint32_t*)alloc((size_t)N_NODES * 4);
    uint32_t* cursors = (uint32_t*)alloc((size_t)N_NODES * 4);
    uint32_t* poff    = (uint32_t*)alloc((size_t)SCAN_NB * 4);
    ushort*   Wpack   = (ushort*)alloc((size_t)12 * 8 * 64 * 8 * 2);
    size_t need = off;

    hipLaunchKernelGGL(k_detect, dim3(1), dim3(64), 0, stream,
                       (const uint32_t*)ei, (const uint32_t*)m1, flags);
    hipLaunchKernelGGL(k_packW, dim3(12), dim3(256), 0, stream, W1, Wpack);

    if (ws_size >= need) {
        // --- CSR path ---
        hipMemsetAsync(deg, 0, (size_t)N_NODES * 4, stream);
        hipLaunchKernelGGL(k_hist, dim3(2048), dim3(256), 0, stream,
                           ei, deg, flags);
        hipLaunchKernelGGL(k_scanA, dim3(SCAN_NB), dim3(256), 0, stream,
                           deg, poff);
        hipLaunchKernelGGL(k_scanB, dim3(1), dim3(512), 0, stream,
                           poff, cursors, starts);  // cursors = block offsets temp
        hipLaunchKernelGGL(k_scanC, dim3(SCAN_NB), dim3(256), 0, stream,
                           deg, cursors, starts);
        hipMemcpyAsync(cursors, starts, (size_t)N_NODES * 4,
                       hipMemcpyDeviceToDevice, stream);
        hipLaunchKernelGGL(k_reorder, dim3(2048), dim3(256), 0, stream,
                           ei, ew, cursors, sorted, flags);
        hipLaunchKernelGGL(k1_mfma, dim3((N_NODES + 63) / 64), dim3(256), 0, stream,
                           x, m1, Wpack, Hb, flags);
        hipLaunchKernelGGL(k_aggmlp, dim3(N_NODES / 4), dim3(256), 0, stream,
                           Hb, sorted, starts, b1, m2, W2, H2b, flags);
        hipLaunchKernelGGL(k_agg, dim3(N_NODES / 4), dim3(256), 0, stream,
                           H2b, sorted, starts, b2, out);
    } else {
        // --- fallback: atomic path ---
        hipMemsetAsync(AGG, 0, (size_t)N_NODES * 64 * 4, stream);
        hipLaunchKernelGGL(k1_mfma, dim3((N_NODES + 63) / 64), dim3(256), 0, stream,
                           x, m1, Wpack, Hb, flags);
        hipLaunchKernelGGL(k_scatter, dim3(4096), dim3(256), 0, stream,
                           Hb, ei, ew, AGG, flags);
        hipLaunchKernelGGL(k3_mlp, dim3(1024), dim3(256), 0, stream,
                           AGG, b1, m2, W2, H2b, flags);
        hipLaunchKernelGGL(k_init_out, dim3(2048), dim3(256), 0, stream, out, b2);
        hipLaunchKernelGGL(k_scatter, dim3(4096), dim3(256), 0, stream,
                           H2b, ei, ew, out, flags);
    }
}